// Round 5
// baseline (344.379 us; speedup 1.0000x reference)
//
#include <hip/hip_runtime.h>
#include <stdint.h>

// ScoreMatching: B=2048, D=64, H=512.
// out[b] = 0.5*||s_b||^2 + tr(W4 M3 W3 M2 W2 M1 W1)_b
// div_b = sum_{i,d} m2[i] * C[i,d] * G[i,d]
//   C = W2 @ (M1 .* W1)      [512 x 64]
//   G = W3^T @ (M3 .* W4^T)  [512 x 64]
// R5: div was L2-BW-bound (4.2 GB @ ~26 TB/s = the 164 us, NOT issue-bound:
// MFMA pipe needs only ~58 us). Fix: 4 samples/block (8 waves) halves A-tile
// re-streaming; B-frags L1-hot across 8 waves. Forward was 1 wave/SIMD
// latency-bound; now 512 thr / 8 samples / thread = 4 units x 2 samples.
// Register budget law (R2 lesson): accC+accG = 128 AGPR + ~104 VGPR = 232
// -> cap 256 regs = 2 waves/SIMD via __launch_bounds__(512,2). Never tighter.

typedef __attribute__((ext_vector_type(8))) short short8;
typedef __attribute__((ext_vector_type(4))) float f32x4;

union U16x8 {
  uint4 u;
  short8 s;
};

__device__ __forceinline__ uint16_t f2bf(float f) {
  uint32_t u = __float_as_uint(f);
  uint32_t lsb = (u >> 16) & 1u;
  u += 0x7FFFu + lsb;  // round-to-nearest-even
  return (uint16_t)(u >> 16);
}

// ---------------- convert: build swizzled bf16 fragments + fp32 transposes ----------------
// Fragment order (16x16x32 bf16 MFMA): lane = quad*16 + l15 holds 8 contiguous
// bf16 = 16 B; A-frag element (m=l15, k=quad*8+j); B-frag (n=l15, k=quad*8+j).
__global__ __launch_bounds__(256) void convert_kernel(
    const float* __restrict__ W1, const float* __restrict__ W2,
    const float* __restrict__ W3, const float* __restrict__ W4,
    uint16_t* __restrict__ A2swz, uint16_t* __restrict__ A3swz,
    uint16_t* __restrict__ B1swz, uint16_t* __restrict__ B4swz,
    float* __restrict__ W2Tf, float* __restrict__ W3Tf,
    float* __restrict__ W1Tf, float* __restrict__ W4Tf) {
  const int i = blockIdx.x * 256 + threadIdx.x;
  if (i < 262144) {  // A2swz
    const int e = i;
    const int f = e >> 3, j = e & 7;
    const int lane = f & 63, fk = f >> 6;
    const int kc = fk & 15, r16 = fk >> 4;
    const int l15 = lane & 15, quad = lane >> 4;
    const int row = r16 * 16 + l15, col = kc * 32 + quad * 8 + j;
    A2swz[e] = f2bf(W2[row * 512 + col]);
  } else if (i < 524288) {  // A3swz (= W3 transposed)
    const int e = i - 262144;
    const int f = e >> 3, j = e & 7;
    const int lane = f & 63, fk = f >> 6;
    const int kc = fk & 15, r16 = fk >> 4;
    const int l15 = lane & 15, quad = lane >> 4;
    const int row = r16 * 16 + l15, col = kc * 32 + quad * 8 + j;
    A3swz[e] = f2bf(W3[col * 512 + row]);
  } else if (i < 557056) {  // B1swz (= W1 transposed)
    const int e = i - 524288;
    const int f = e >> 3, j = e & 7;
    const int lane = f & 63, fk = f >> 6;
    const int kc = fk >> 2, jt = fk & 3;
    const int l15 = lane & 15, quad = lane >> 4;
    const int d = jt * 16 + l15, col = kc * 32 + quad * 8 + j;
    B1swz[e] = f2bf(W1[col * 64 + d]);
  } else if (i < 589824) {  // B4swz (= W4 row-major)
    const int e = i - 557056;
    const int f = e >> 3, j = e & 7;
    const int lane = f & 63, fk = f >> 6;
    const int kc = fk >> 2, jt = fk & 3;
    const int l15 = lane & 15, quad = lane >> 4;
    const int d = jt * 16 + l15, col = kc * 32 + quad * 8 + j;
    B4swz[e] = f2bf(W4[d * 512 + col]);
  } else if (i < 851968) {  // W2Tf [k][j]
    const int e = i - 589824;
    const int k = e >> 9, jj = e & 511;
    W2Tf[e] = W2[jj * 512 + k];
  } else if (i < 1114112) {  // W3Tf [k][j]
    const int e = i - 851968;
    const int k = e >> 9, jj = e & 511;
    W3Tf[e] = W3[jj * 512 + k];
  } else if (i < 1146880) {  // W1Tf [k][j], k<64
    const int e = i - 1114112;
    const int k = e >> 9, jj = e & 511;
    W1Tf[e] = W1[jj * 64 + k];
  } else if (i < 1179648) {  // W4Tf [k][d]
    const int e = i - 1146880;
    const int k = e >> 6, d = e & 63;
    W4Tf[e] = W4[d * 512 + k];
  }
}

// ---------------- forward (fp32): packed masks + 0.5*||s||^2 ----------------
// 512 threads = 8 waves, 8 samples/block, 256 blocks (1 block/CU, 2 waves/SIMD).
// Thread: g = t>>7 (sample pair), q = t&127 -> units q*4..q*4+3, samples 2g,2g+1.
// Per k: 8 B LDS broadcast (2 samples) + 16 B coalesced VMEM (4 units) -> 8 FMA.
// Masks: nibble atomicOr into LDS u32 words; bit u of word w = unit w*32+u.
__global__ __launch_bounds__(512) void forward_kernel(
    const float* __restrict__ x,
    const float* __restrict__ W1Tf, const float* __restrict__ b1,
    const float* __restrict__ W2Tf, const float* __restrict__ b2,
    const float* __restrict__ W3Tf, const float* __restrict__ b3,
    const float* __restrict__ W4Tf, const float* __restrict__ b4,
    uint32_t* __restrict__ m1p, uint32_t* __restrict__ m2p,
    uint32_t* __restrict__ m3p, float* __restrict__ out) {
  __shared__ float2 xs2[4][64];      // [pair][k]
  __shared__ float2 hp[2][4][512];   // [buf][pair][unit]
  __shared__ uint32_t mw[128];       // [sample][16 words]
  const int t = threadIdx.x;
  const int b0 = blockIdx.x * 8;
  const int g = t >> 7;
  const int q = t & 127;
  const int j4 = q * 4;
  const int word = q >> 3, shift = (q & 7) * 4;

  {
    const int s = t >> 6, k = t & 63;
    ((float*)&xs2[s >> 1][k])[s & 1] = x[(size_t)(b0 + s) * 64 + k];
    if (t < 128) mw[t] = 0;
  }
  __syncthreads();

  float a[4][2];

#define FWD_LAYER(WT, BIAS, SRC, DSTBUF, MGLOB, KDIM)                          \
  {                                                                            \
    const float4 bb = *(const float4*)((BIAS) + j4);                           \
    a[0][0] = bb.x; a[0][1] = bb.x; a[1][0] = bb.y; a[1][1] = bb.y;            \
    a[2][0] = bb.z; a[2][1] = bb.z; a[3][0] = bb.w; a[3][1] = bb.w;            \
    _Pragma("unroll 4") for (int k = 0; k < (KDIM); ++k) {                     \
      const float4 w = *(const float4*)((WT) + (size_t)k * 512 + j4);          \
      const float2 h = (SRC)[k];                                               \
      a[0][0] = fmaf(w.x, h.x, a[0][0]); a[0][1] = fmaf(w.x, h.y, a[0][1]);    \
      a[1][0] = fmaf(w.y, h.x, a[1][0]); a[1][1] = fmaf(w.y, h.y, a[1][1]);    \
      a[2][0] = fmaf(w.z, h.x, a[2][0]); a[2][1] = fmaf(w.z, h.y, a[2][1]);    \
      a[3][0] = fmaf(w.w, h.x, a[3][0]); a[3][1] = fmaf(w.w, h.y, a[3][1]);    \
    }                                                                          \
    uint32_t nib0 = (a[0][0] > 0.f ? 1u : 0u) | (a[1][0] > 0.f ? 2u : 0u) |    \
                    (a[2][0] > 0.f ? 4u : 0u) | (a[3][0] > 0.f ? 8u : 0u);     \
    uint32_t nib1 = (a[0][1] > 0.f ? 1u : 0u) | (a[1][1] > 0.f ? 2u : 0u) |    \
                    (a[2][1] > 0.f ? 4u : 0u) | (a[3][1] > 0.f ? 8u : 0u);     \
    if (nib0) atomicOr(&mw[(2 * g) * 16 + word], nib0 << shift);               \
    if (nib1) atomicOr(&mw[(2 * g + 1) * 16 + word], nib1 << shift);           \
    _Pragma("unroll") for (int u = 0; u < 4; ++u) {                            \
      hp[DSTBUF][g][j4 + u] =                                                  \
          make_float2(a[u][0] > 0.f ? a[u][0] : 0.f,                           \
                      a[u][1] > 0.f ? a[u][1] : 0.f);                          \
    }                                                                          \
    __syncthreads();                                                           \
    if (t < 128) {                                                             \
      (MGLOB)[(size_t)(b0 + (t >> 4)) * 16 + (t & 15)] = mw[t];                \
      mw[t] = 0;                                                               \
    }                                                                          \
    __syncthreads();                                                           \
  }

  FWD_LAYER(W1Tf, b1, xs2[g], 0, m1p, 64)
  FWD_LAYER(W2Tf, b2, hp[0][g], 1, m2p, 512)
  FWD_LAYER(W3Tf, b3, hp[1][g], 0, m3p, 512)
#undef FWD_LAYER

  // ---- layer 4 (K=512, D=64) + 0.5*||s||^2 : wave wv -> sample b0+wv ----
  {
    const int wv = t >> 6, lane = t & 63;
    const int d = lane;
    const int gg = wv >> 1, c = wv & 1;
    float acc = b4[d];
#pragma unroll 4
    for (int k = 0; k < 512; ++k) {
      const float h = ((const float*)&hp[0][gg][k])[c];
      acc = fmaf(W4Tf[k * 64 + d], h, acc);
    }
    float sq = acc * acc;
#pragma unroll
    for (int off = 32; off; off >>= 1) sq += __shfl_down(sq, off, 64);
    if (d == 0) out[b0 + wv] = 0.5f * sq;
  }
}

// ---------------- divergence: barrier-free dual bf16 MFMA stream ----------------
// grid (512 sample-quads, 4 row-tiles of 128); block 512 = 8 waves.
// wave (sLoc=wv&3, rh=wv>>2): sample g*4+sLoc, rows rowB0+rh*64..+64, cols 0..64.
// Pre-swizzled coalesced 1KB fragment loads; no LDS, no barriers. 4 samples/block
// halves A-tile L2 traffic vs 2-sample blocks; B-frags shared by all 8 waves (L1).
__device__ __forceinline__ void expand_mask(uint32_t byte8, uint32_t mk[4]) {
#pragma unroll
  for (int i = 0; i < 4; ++i) {
    mk[i] = (((byte8 >> (2 * i)) & 1u) ? 0x0000FFFFu : 0u) |
            (((byte8 >> (2 * i + 1)) & 1u) ? 0xFFFF0000u : 0u);
  }
}

__global__ __launch_bounds__(512, 2) void div_kernel(
    const uint4* __restrict__ A2swz, const uint4* __restrict__ A3swz,
    const uint4* __restrict__ B1swz, const uint4* __restrict__ B4swz,
    const uint32_t* __restrict__ m1p, const uint32_t* __restrict__ m2p,
    const uint32_t* __restrict__ m3p, float* __restrict__ out) {
  const int t = threadIdx.x;
  const int lane = t & 63, wv = t >> 6;
  const int sLoc = wv & 3, rh = wv >> 2;
  const int l15 = lane & 15, quad = lane >> 4;
  const int g = blockIdx.x;
  const int rowB0 = blockIdx.y * 128;
  const int b = g * 4 + sLoc;
  const int r16b = (rowB0 >> 4) + rh * 4;

  f32x4 accC[4][4], accG[4][4];
#pragma unroll
  for (int it = 0; it < 4; ++it)
#pragma unroll
    for (int jt = 0; jt < 4; ++jt) {
      accC[it][jt] = (f32x4){0.f, 0.f, 0.f, 0.f};
      accG[it][jt] = (f32x4){0.f, 0.f, 0.f, 0.f};
    }

  const uint32_t* m1w = m1p + (size_t)b * 16;
  const uint32_t* m3w = m3p + (size_t)b * 16;

#pragma unroll 1
  for (int kc = 0; kc < 16; ++kc) {
    uint4 a2[4], u1[4], a3[4], u4[4];
    // C-group loads first, G-group second: C-MFMAs overlap in-flight G loads.
#pragma unroll
    for (int it = 0; it < 4; ++it)
      a2[it] = A2swz[(size_t)((r16b + it) * 16 + kc) * 64 + lane];
#pragma unroll
    for (int jt = 0; jt < 4; ++jt)
      u1[jt] = B1swz[(size_t)(kc * 4 + jt) * 64 + lane];
#pragma unroll
    for (int it = 0; it < 4; ++it)
      a3[it] = A3swz[(size_t)((r16b + it) * 16 + kc) * 64 + lane];
#pragma unroll
    for (int jt = 0; jt < 4; ++jt)
      u4[jt] = B4swz[(size_t)(kc * 4 + jt) * 64 + lane];

    const uint32_t m1d = __builtin_amdgcn_readfirstlane(m1w[kc]);
    const uint32_t m3d = __builtin_amdgcn_readfirstlane(m3w[kc]);
    uint32_t mk1[4], mk3[4];
    expand_mask((m1d >> (quad * 8)) & 0xFFu, mk1);
    expand_mask((m3d >> (quad * 8)) & 0xFFu, mk3);

    short8 bC[4];
#pragma unroll
    for (int jt = 0; jt < 4; ++jt) {
      U16x8 u;
      u.u = u1[jt];
      u.u.x &= mk1[0]; u.u.y &= mk1[1]; u.u.z &= mk1[2]; u.u.w &= mk1[3];
      bC[jt] = u.s;
    }
#pragma unroll
    for (int it = 0; it < 4; ++it) {
      U16x8 ua;
      ua.u = a2[it];
      const short8 af = ua.s;
#pragma unroll
      for (int jt = 0; jt < 4; ++jt)
        accC[it][jt] = __builtin_amdgcn_mfma_f32_16x16x32_bf16(af, bC[jt], accC[it][jt], 0, 0, 0);
    }
    short8 bG[4];
#pragma unroll
    for (int jt = 0; jt < 4; ++jt) {
      U16x8 u;
      u.u = u4[jt];
      u.u.x &= mk3[0]; u.u.y &= mk3[1]; u.u.z &= mk3[2]; u.u.w &= mk3[3];
      bG[jt] = u.s;
    }
#pragma unroll
    for (int it = 0; it < 4; ++it) {
      U16x8 ua;
      ua.u = a3[it];
      const short8 af = ua.s;
#pragma unroll
      for (int jt = 0; jt < 4; ++jt)
        accG[it][jt] = __builtin_amdgcn_mfma_f32_16x16x32_bf16(af, bG[jt], accG[it][jt], 0, 0, 0);
    }
  }

  // epilogue: dsum = sum m2[row] * C .* G ; C/D layout: row = quad*4+reg, col = l15
  const uint32_t* m2w = m2p + (size_t)b * 16;
  float dsum = 0.f;
#pragma unroll
  for (int it = 0; it < 4; ++it) {
    const int rloc = rh * 64 + it * 16 + quad * 4;
    const uint32_t md = m2w[(rowB0 + rloc) >> 5];
    const uint32_t bits = (md >> (rloc & 31)) & 0xFu;
    const float w0 = (bits & 1u) ? 1.f : 0.f;
    const float w1 = (bits & 2u) ? 1.f : 0.f;
    const float w2 = (bits & 4u) ? 1.f : 0.f;
    const float w3 = (bits & 8u) ? 1.f : 0.f;
#pragma unroll
    for (int jt = 0; jt < 4; ++jt) {
      dsum = fmaf(w0, accC[it][jt][0] * accG[it][jt][0], dsum);
      dsum = fmaf(w1, accC[it][jt][1] * accG[it][jt][1], dsum);
      dsum = fmaf(w2, accC[it][jt][2] * accG[it][jt][2], dsum);
      dsum = fmaf(w3, accC[it][jt][3] * accG[it][jt][3], dsum);
    }
  }
#pragma unroll
  for (int off = 32; off; off >>= 1) dsum += __shfl_down(dsum, off, 64);
  if (lane == 0) atomicAdd(out + b, dsum);
}

extern "C" void kernel_launch(void* const* d_in, const int* in_sizes, int n_in,
                              void* d_out, int out_size, void* d_ws, size_t ws_size,
                              hipStream_t stream) {
  const float* x  = (const float*)d_in[0];
  const float* W1 = (const float*)d_in[1];
  const float* b1 = (const float*)d_in[2];
  const float* W2 = (const float*)d_in[3];
  const float* b2 = (const float*)d_in[4];
  const float* W3 = (const float*)d_in[5];
  const float* b3 = (const float*)d_in[6];
  const float* W4 = (const float*)d_in[7];
  const float* b4 = (const float*)d_in[8];
  float* out = (float*)d_out;

  // workspace layout (bytes), total 3,932,160:
  char* ws = (char*)d_ws;
  uint16_t* A2swz = (uint16_t*)(ws + 0);        // 524288
  uint16_t* A3swz = (uint16_t*)(ws + 524288);   // 524288
  uint16_t* B1swz = (uint16_t*)(ws + 1048576);  // 65536
  uint16_t* B4swz = (uint16_t*)(ws + 1114112);  // 65536
  float*    W2Tf  = (float*)(ws + 1179648);     // 1048576
  float*    W3Tf  = (float*)(ws + 2228224);     // 1048576
  float*    W1Tf  = (float*)(ws + 3276800);     // 131072
  float*    W4Tf  = (float*)(ws + 3407872);     // 131072
  uint32_t* m1p   = (uint32_t*)(ws + 3538944);  // 131072 (2048 x 512 bits)
  uint32_t* m2p   = (uint32_t*)(ws + 3670016);  // 131072
  uint32_t* m3p   = (uint32_t*)(ws + 3801088);  // 131072
  if (ws_size < 3932160) return;

  convert_kernel<<<4608, 256, 0, stream>>>(W1, W2, W3, W4,
                                           A2swz, A3swz, B1swz, B4swz,
                                           W2Tf, W3Tf, W1Tf, W4Tf);
  forward_kernel<<<256, 512, 0, stream>>>(x, W1Tf, b1, W2Tf, b2, W3Tf, b3,
                                          W4Tf, b4, m1p, m2p, m3p, out);
  div_kernel<<<dim3(512, 4), 512, 0, stream>>>((const uint4*)A2swz,
                                               (const uint4*)A3swz,
                                               (const uint4*)B1swz,
                                               (const uint4*)B4swz,
                                               m1p, m2p, m3p, out);
}